// Round 1
// 320.381 us; speedup vs baseline: 1.0868x; 1.0868x over previous
//
#include <hip/hip_runtime.h>
#include <hip/hip_fp16.h>
#include <math.h>

#define L_SIG 65537
#define NH    65536     // half-size complex FFT length (NFFT/2)
#define NSIG  256
#define PI_F  3.14159265358979323846f

struct alignas(8) c32 { float x, y; };   // 8B-aligned -> LDS ds_*_b64
typedef __half2 h2;
__device__ __forceinline__ c32 mkc(float a, float b){ c32 r; r.x=a; r.y=b; return r; }
__device__ __forceinline__ c32 cadd(c32 a, c32 b){ return mkc(a.x+b.x, a.y+b.y); }
__device__ __forceinline__ c32 csub(c32 a, c32 b){ return mkc(a.x-b.x, a.y-b.y); }
__device__ __forceinline__ c32 cmul(c32 a, c32 b){ return mkc(a.x*b.x - a.y*b.y, a.x*b.y + a.y*b.x); }
__device__ __forceinline__ h2  c2h(c32 a){ return __floats2half2_rn(a.x, a.y); }
__device__ __forceinline__ c32 h2c(h2 a){ float2 f = __half22float2(a); return mkc(f.x, f.y); }

// ---------------- 16-point FFT in registers (radix-4 x 2) ------------------
template<int S>
__device__ __forceinline__ void fft16(c32 v[16]) {
  constexpr float C16[16] = {
    1.0f, 0.9238795325112867f, 0.7071067811865476f, 0.3826834323650898f,
    0.0f,-0.3826834323650898f,-0.7071067811865476f,-0.9238795325112867f,
   -1.0f,-0.9238795325112867f,-0.7071067811865476f,-0.3826834323650898f,
    0.0f, 0.3826834323650898f, 0.7071067811865476f, 0.9238795325112867f };
  constexpr float S16[16] = {
    0.0f, 0.3826834323650898f, 0.7071067811865476f, 0.9238795325112867f,
    1.0f, 0.9238795325112867f, 0.7071067811865476f, 0.3826834323650898f,
    0.0f,-0.3826834323650898f,-0.7071067811865476f,-0.9238795325112867f,
   -1.0f,-0.9238795325112867f,-0.7071067811865476f,-0.3826834323650898f };
  c32 s[16];
  #pragma unroll
  for (int b0 = 0; b0 < 4; ++b0) {
    c32 x0=v[b0], x1=v[b0+4], x2=v[b0+8], x3=v[b0+12];
    c32 u0=cadd(x0,x2), u1=csub(x0,x2), u2=cadd(x1,x3), u3=csub(x1,x3);
    c32 iu3 = mkc(-u3.y, u3.x);
    c32 yy[4];
    yy[0]=cadd(u0,u2); yy[2]=csub(u0,u2);
    if (S < 0) { yy[1]=csub(u1,iu3); yy[3]=cadd(u1,iu3); }
    else       { yy[1]=cadd(u1,iu3); yy[3]=csub(u1,iu3); }
    #pragma unroll
    for (int c0 = 0; c0 < 4; ++c0) {
      const int p = (b0*c0) & 15;
      c32 w = mkc(C16[p], (S<0) ? -S16[p] : S16[p]);
      s[c0*4 + b0] = cmul(yy[c0], w);
    }
  }
  #pragma unroll
  for (int c0 = 0; c0 < 4; ++c0) {
    c32 x0=s[c0*4+0], x1=s[c0*4+1], x2=s[c0*4+2], x3=s[c0*4+3];
    c32 u0=cadd(x0,x2), u1=csub(x0,x2), u2=cadd(x1,x3), u3=csub(x1,x3);
    c32 iu3 = mkc(-u3.y, u3.x);
    c32 yy[4];
    yy[0]=cadd(u0,u2); yy[2]=csub(u0,u2);
    if (S < 0) { yy[1]=csub(u1,iu3); yy[3]=cadd(u1,iu3); }
    else       { yy[1]=cadd(u1,iu3); yy[3]=csub(u1,iu3); }
    v[c0+0]=yy[0]; v[c0+4]=yy[1]; v[c0+8]=yy[2]; v[c0+12]=yy[3];
  }
}

// ------------- 256-pt FFT, 16-thread team, c32(b64) XOR-swizzled LDS ------
// Banks (b64 view): write idx%16 = t ^ 8*(c&1); read idx%16 = t ^ 8*(r&1)
// -> 4 lanes per bank-pair = the 512B/wave-instr floor, no extra conflicts.
template<int S>
__device__ __forceinline__ void fft256_team(c32 v[16], int r, int t, c32* sc) {
  fft16<S>(v);
  float ang = (float)S * (2.0f*PI_F/256.0f) * (float)r;
  c32 st; __sincosf(ang, &st.y, &st.x);
  c32 w = st;
  #pragma unroll
  for (int c = 1; c < 16; ++c) { v[c] = cmul(v[c], w); w = cmul(w, st); }
  __syncthreads();
  #pragma unroll
  for (int c = 0; c < 16; ++c) {
    int idx = c*256 + ((r*16 + t) ^ ((c & 3) << 3));
    sc[idx] = v[c];
  }
  __syncthreads();
  #pragma unroll
  for (int a = 0; a < 16; ++a) {
    int idx = r*256 + ((a*16 + t) ^ ((r & 3) << 3));
    v[a] = sc[idx];
  }
  fft16<S>(v);
}

// ---------------- prep: mod_depth, pm, spectral line table ----------------
__global__ __launch_bounds__(256) void k_prep(const float* __restrict__ b1,
    const float* __restrict__ W2, const float* __restrict__ b2,
    const float* __restrict__ W3, const float* __restrict__ b3,
    const float* __restrict__ hp, const float* __restrict__ fw,
    float* __restrict__ pm_out, int* __restrict__ hidx, float* __restrict__ amp) {
  __shared__ float red[256];
  __shared__ float s_md, s_pm;
  int t = threadIdx.x;
  if (t == 0) {
    float h1[32], h2v[16];
    for (int i=0;i<32;i++){ float z = b1[i]; h1[i] = z > 0.f ? z : 0.f; }
    for (int o=0;o<16;o++){ float acc = b2[o];
      for (int i=0;i<32;i++) acc += h1[i]*W2[i*16+o];
      h2v[o] = acc > 0.f ? acc : 0.f; }
    float md = b3[1];
    for (int i=0;i<16;i++) md += h2v[i]*W3[i*8+1];
    s_md = md;
  }
  __syncthreads();
  float md = s_md;
  float partial = 0.f;
  for (int tt = t; tt < 65537; tt += 256) {
    int ci = (tt * 8) / 65537;
    float cs = hp[ci*4+0] + hp[ci*4+1] + hp[ci*4+2] + hp[ci*4+3];
    float ang = (6.2831853071795864769f * (float)tt) / 65537.0f;
    partial += cs * (1.f + md * sinf(ang));
  }
  red[t] = partial;
  __syncthreads();
  for (int s = 128; s > 0; s >>= 1) { if (t < s) red[t] += red[t+s]; __syncthreads(); }
  if (t == 0) { s_pm = red[0] / (65537.0f * 4.0f); pm_out[0] = s_pm; }
  __syncthreads();
  if (t < 40) {
    const double SPECF[8] = {7.83, 528.0, 396.0, 2.5, 14.1, 432.0, 6.0, 30.0};
    int j = t / 5, mi = t % 5;
    double mult = (double)(mi + 1);
    double hf = SPECF[j] * mult;
    double ratio = hf * (131072.0 / 22050.0);
    hidx[t] = (int)floor(ratio + 0.5);
    amp[t] = (float)((double)fw[j] * pow(mult, -1.2) * (1.0 + (double)s_pm));
  }
}

// ---------------- gain curve: bands + 40 spectral line windows ------------
__global__ __launch_bounds__(256) void k_gain(float* __restrict__ gain,
    const float* __restrict__ bw, const int* __restrict__ hidx,
    const float* __restrict__ amp) {
  int i = blockIdx.x*256 + threadIdx.x;
  if (i >= 65537) return;
  float f = (float)((double)i * (22050.0/131072.0));
  float g = 1.0f;
  constexpr double LO[6] = {1,4,8,13,30,100};
  constexpr double HI[6] = {4,8,13,30,100,200};
  #pragma unroll
  for (int k = 0; k < 6; ++k) {
    float center = (float)(0.5*(LO[k]+HI[k]));
    float sig    = (float)(0.25*(HI[k]-LO[k]));
    float dm = (f - center)/sig;
    float mask = expf(-0.5f*dm*dm);
    if (f < (float)LO[k] || f > (float)HI[k]) mask = 0.f;
    float ang = (float)(6.283185307179586*0.5*(LO[k]+HI[k])) * (float)i / 22050.0f;
    g *= 1.0f + mask * bw[k] * (1.0f + 0.2f*sinf(ang));
  }
  for (int l = 0; l < 40; ++l) {
    int d = i - hidx[l];
    if (d >= -15 && d <= 15) {
      float dd = (float)d * 0.2f;
      g *= 1.0f + amp[l] * expf(-0.5f*dd*dd);
    }
  }
  gain[i] = g;
}

// ---------------- forward pass 1: pack + column FFT + 4-step twiddle ------
__global__ __launch_bounds__(256) void k_fwd1(const float* __restrict__ x,
                                              h2* __restrict__ A, int s0) {
  __shared__ c32 sc[4096];           // 32 KB
  int b = blockIdx.x; int sl = b >> 4; int g = b & 15;
  int t = threadIdx.x & 15, r = threadIdx.x >> 4;
  int n1 = g*16 + t;
  const float* xb = x + (size_t)(s0 + sl) * L_SIG;
  c32 v[16];
  #pragma unroll
  for (int j = 0; j < 16; ++j) {
    int n = n1 + 256*r + 4096*j;
    c32 z = mkc(0.f, 0.f);
    if (n < 32768)       { z.x = xb[2*n]; z.y = xb[2*n+1]; }
    else if (n == 32768) { z.x = xb[65536]; }
    v[j] = z;
  }
  fft256_team<-1>(v, r, t, sc);
  float a0 = -(2.0f*PI_F/65536.0f) * (float)(n1 * r);
  float a1 = -(2.0f*PI_F/4096.0f)  * (float)n1;
  c32 wb, wst;
  __sincosf(a0, &wb.y, &wb.x);
  __sincosf(a1, &wst.y, &wst.x);
  #pragma unroll
  for (int j = 0; j < 16; ++j) { v[j] = cmul(v[j], wb); wb = cmul(wb, wst); }
  // stage + coalesced store: A[sl][k2*256 + n1]
  __syncthreads();
  #pragma unroll
  for (int j = 0; j < 16; ++j)
    sc[(r + 16*j)*16 + t] = v[j];     // bank-pair = t : floor
  __syncthreads();
  h2* Ab = A + (size_t)sl * NH;
  int u = threadIdx.x & 15, k2b = threadIdx.x >> 4;
  #pragma unroll
  for (int m = 0; m < 16; ++m) {
    int k2 = k2b + 16*m;
    Ab[(size_t)k2*256 + g*16 + u] = c2h(sc[k2*16 + u]);
  }
}

// ---------------- forward pass 2: row FFT -> Z natural order --------------
// stage-in: stg (h2, stride 260) aliases the team-FFT scratch (safe: fragments
// are in registers before fft256_team's first interior barrier).
__global__ __launch_bounds__(256) void k_fwd2(const h2* __restrict__ A,
                                              h2* __restrict__ B) {
  __shared__ c32 sc[4096];           // 32 KB; first 16.25 KB aliased as stg
  h2* stg = (h2*)sc;
  int b = blockIdx.x; int sl = b >> 4; int g = b & 15;
  int tid = threadIdx.x;
  int t = tid & 15, r = tid >> 4;
  const h2* Ab = A + (size_t)sl * NH;
  #pragma unroll
  for (int m = 0; m < 4; ++m) {
    int flat = tid + 256*m;
    int row = flat >> 6, i = flat & 63;
    float4 z = ((const float4*)(Ab + (size_t)(g*16 + row)*256))[i];
    *((float4*)&stg[row*260 + 4*i]) = z;   // 16B aligned, conflict-free
  }
  __syncthreads();
  c32 v[16];
  #pragma unroll
  for (int j = 0; j < 16; ++j)
    v[j] = h2c(stg[t*260 + r + 16*j]);     // banks (4t+r+16j)%32 : 2-way
  fft256_team<-1>(v, r, t, sc);
  h2* Bb = B + (size_t)sl * NH;
  int k2 = g*16 + t;
  #pragma unroll
  for (int j = 0; j < 16; ++j) Bb[(size_t)k2 + 256*(r + 16*j)] = c2h(v[j]);
}

// ---------------- mid: unpack + gain + mag smooth + repack + 1/N ----------
// Conjugate-pair sharing: with A=(zk+conj(zb))/2, B=(zk-conj(zb))/2 and
// w = -i e^{-i pi k/NH}:  X[k] = A + wB  and  X[NH-k] = conj(A - wB).
// One sincos + one cmul yields BOTH bins. Bins stored as unit-phase U and
// gained magnitude m (rsqrt, no sqrt/div); repack twiddle = stashed conj.
__global__ __launch_bounds__(256) void k_mid(const h2* __restrict__ Z,
    h2* __restrict__ Zc, const float* __restrict__ gain) {
  __shared__ c32 XL[258], XH[258];     // unit-phase vectors
  __shared__ float ML[258], MH[258];   // gained magnitudes
  __shared__ float TC[258], TS[258];   // cos/sin(pi*k/65536) at bin k=k0-1+e
  int b = blockIdx.x; int s = b >> 7; int blk = b & 127;
  int k0 = blk << 8;
  const h2* Zs = Z + (size_t)s * NH;
  h2* Os = Zc + (size_t)s * NH;
  int t = threadIdx.x;
  for (int e = t; e < 258; e += 256) {
    int k = k0 - 1 + e;                // bin for XL[e]; mirror NH-k -> XH[257-e]
    bool kv = (k >= 0);                // k==-1 only at blk==0,e==0 (mirror NH+1 also invalid)
    int kc = kv ? k : 0;
    c32 zk = h2c(Zs[k & (NH-1)]);
    c32 zb = h2c(Zs[(NH - k) & (NH-1)]);
    c32 Aa = mkc(0.5f*(zk.x + zb.x), 0.5f*(zk.y - zb.y));
    c32 Bm = mkc(0.5f*(zk.x - zb.x), 0.5f*(zk.y + zb.y));
    float sn, cn; __sincosf((PI_F/65536.0f)*(float)k, &sn, &cn);
    TC[e] = cn; TS[e] = sn;
    c32 wB = cmul(mkc(-sn, -cn), Bm);  // (-i e^{-i th}) * B
    float gk = gain[kc];
    float gK = gain[NH - kc];
    c32 Xk = mkc((Aa.x + wB.x)*gk,  (Aa.y + wB.y)*gk);    // X[k]*g[k]
    c32 XK = mkc((Aa.x - wB.x)*gK, -(Aa.y - wB.y)*gK);    // X[NH-k]*g[NH-k]
    float nk = Xk.x*Xk.x + Xk.y*Xk.y;
    float nK = XK.x*XK.x + XK.y*XK.y;
    float rk = rsqrtf(nk), rK = rsqrtf(nK);
    c32 Uk = (nk > 0.f) ? mkc(Xk.x*rk, Xk.y*rk) : mkc(1.f, 0.f);
    c32 UK = (nK > 0.f) ? mkc(XK.x*rK, XK.y*rK) : mkc(1.f, 0.f);
    float mk = (kv && nk > 0.f) ? nk*rk : 0.f;            // = |X|*g
    float mK = (kv && nK > 0.f) ? nK*rK : 0.f;
    XL[e] = Uk;  ML[e] = mk;
    XH[257-e] = UK; MH[257-e] = mK;
  }
  __syncthreads();
  {
    int q = t; int k = k0 + q;
    float m = ML[q+1];
    float msm = (k == 0) ? m : 0.7f*m + 0.15f*(ML[q] + ML[q+2]);
    c32 U = XL[q+1];
    c32 XcL = mkc(U.x*msm, U.y*msm);
    int K = NH - k;
    int eH = 256 - q;
    float mh = MH[eH];
    float msh = (K == 65536) ? mh : 0.7f*mh + 0.15f*(MH[eH-1] + MH[eH+1]);
    c32 Uh = XH[eH];
    c32 XcH = mkc(Uh.x*msh, Uh.y*msh);
    // E' = 0.5(XcL + conj(XcH)); O' = 0.5 W^{-k} (XcL - conj(XcH))
    c32 E = mkc(0.5f*(XcL.x + XcH.x), 0.5f*(XcL.y - XcH.y));
    c32 D = mkc(0.5f*(XcL.x - XcH.x), 0.5f*(XcL.y + XcH.y));
    c32 O = cmul(mkc(TC[q+1], TS[q+1]), D);   // e^{+i pi k/NH} = conj(unpack tw)
    const float invN = 1.0f/65536.0f;
    Os[k] = c2h(mkc((E.x - O.y)*invN, (E.y + O.x)*invN));              // E' + iO'
    if (k != 0) Os[K] = c2h(mkc((E.x + O.y)*invN, (O.x - E.y)*invN));  // conj pack
  }
  if (blk == 127 && t == 0) {   // self-paired bin k = 32768
    float m = ML[257];
    float msm = 0.7f*m + 0.15f*(ML[256] + MH[1]);
    c32 U = XL[257];
    const float invN = 1.0f/65536.0f;
    Os[32768] = c2h(mkc(U.x*msm*invN, -U.y*msm*invN));
  }
}

// ---------------- inverse pass 1: column FFT (+) + twiddle ----------------
__global__ __launch_bounds__(256) void k_inv1(const h2* __restrict__ Zc,
                                              h2* __restrict__ B) {
  __shared__ c32 sc[4096];
  int b = blockIdx.x; int sl = b >> 4; int g = b & 15;
  int t = threadIdx.x & 15, r = threadIdx.x >> 4;
  int a = g*16 + t;
  const h2* Zs = Zc + (size_t)sl * NH;
  c32 v[16];
  #pragma unroll
  for (int j = 0; j < 16; ++j) v[j] = h2c(Zs[(size_t)a + 256*(r + 16*j)]);
  fft256_team<1>(v, r, t, sc);
  float a0 = (2.0f*PI_F/65536.0f) * (float)(a * r);
  float a1 = (2.0f*PI_F/4096.0f)  * (float)a;
  c32 wb, wst;
  __sincosf(a0, &wb.y, &wb.x);
  __sincosf(a1, &wst.y, &wst.x);
  #pragma unroll
  for (int j = 0; j < 16; ++j) { v[j] = cmul(v[j], wb); wb = cmul(wb, wst); }
  __syncthreads();
  #pragma unroll
  for (int j = 0; j < 16; ++j)
    sc[(r + 16*j)*16 + t] = v[j];
  __syncthreads();
  h2* Bb = B + (size_t)sl * NH;
  int u = threadIdx.x & 15, m2b = threadIdx.x >> 4;
  #pragma unroll
  for (int m = 0; m < 16; ++m) {
    int m2 = m2b + 16*m;
    Bb[(size_t)m2*256 + g*16 + u] = c2h(sc[m2*16 + u]);
  }
}

// ---------------- inverse pass 2: row FFT (+) -> real output --------------
__global__ __launch_bounds__(256) void k_inv2(const h2* __restrict__ B,
                                              float* __restrict__ out, int s0) {
  __shared__ c32 sc[4096];
  h2* stg = (h2*)sc;
  int b = blockIdx.x; int sl = b >> 4; int g = b & 15;
  int tid = threadIdx.x;
  int t = tid & 15, r = tid >> 4;
  const h2* Bb = B + (size_t)sl * NH;
  #pragma unroll
  for (int m = 0; m < 4; ++m) {
    int flat = tid + 256*m;
    int row = flat >> 6, i = flat & 63;
    float4 z = ((const float4*)(Bb + (size_t)(g*16 + row)*256))[i];
    *((float4*)&stg[row*260 + 4*i]) = z;
  }
  __syncthreads();
  c32 v[16];
  #pragma unroll
  for (int j = 0; j < 16; ++j)
    v[j] = h2c(stg[t*260 + r + 16*j]);
  fft256_team<1>(v, r, t, sc);
  float* yb = out + (size_t)(s0 + sl) * L_SIG;
  int m2 = g*16 + t;
  #pragma unroll
  for (int j = 0; j < 16; ++j) {
    int m1 = r + 16*j;
    if (m1 <= 127) {
      int m = m2 + 256*m1;
      yb[2*m]   = v[j].x;
      yb[2*m+1] = v[j].y;
    } else if (m1 == 128 && m2 == 0) {
      yb[65536] = v[j].x;
    }
  }
}

// --------------------------------------------------------------------------
extern "C" void kernel_launch(void* const* d_in, const int* in_sizes, int n_in,
                              void* d_out, int out_size, void* d_ws, size_t ws_size,
                              hipStream_t stream) {
  const float* x  = (const float*)d_in[0];
  const float* bw = (const float*)d_in[1];
  const float* fw = (const float*)d_in[2];
  const float* hp = (const float*)d_in[3];
  // d_in[4] = W1: mathematically unused (tn==0 at the only sampled row)
  const float* b1 = (const float*)d_in[5];
  const float* W2 = (const float*)d_in[6];
  const float* b2 = (const float*)d_in[7];
  const float* W3 = (const float*)d_in[8];
  const float* b3 = (const float*)d_in[9];
  float* out = (float*)d_out;
  char* ws = (char*)d_ws;

  const size_t perSig = (size_t)NH * sizeof(h2);              // 256 KiB / signal / buffer
  const size_t tail   = (size_t)L_SIG * sizeof(float) + 1024; // gain + scalars
  size_t cap = (ws_size > tail) ? (ws_size - tail) / (2*perSig) : 1;
  int chunk = (cap >= (size_t)NSIG) ? NSIG : (cap < 1 ? 1 : (int)cap);

  h2*    A    = (h2*)ws;
  h2*    Bb   = (h2*)(ws + (size_t)chunk*perSig);
  float* gain = (float*)(ws + 2*(size_t)chunk*perSig);
  float* pm   = gain + L_SIG;
  int*   hidx = (int*)(pm + 1);
  float* amp  = (float*)(hidx + 40);

  k_prep<<<1, 256, 0, stream>>>(b1, W2, b2, W3, b3, hp, fw, pm, hidx, amp);
  k_gain<<<257, 256, 0, stream>>>(gain, bw, hidx, amp);

  for (int s0 = 0; s0 < NSIG; s0 += chunk) {
    int S = (NSIG - s0 < chunk) ? (NSIG - s0) : chunk;
    k_fwd1<<<S*16, 256, 0, stream>>>(x, A, s0);
    k_fwd2<<<S*16, 256, 0, stream>>>(A, Bb);
    k_mid <<<S*128,256, 0, stream>>>(Bb, A, gain);
    k_inv1<<<S*16, 256, 0, stream>>>(A, Bb);
    k_inv2<<<S*16, 256, 0, stream>>>(Bb, out, s0);
  }
}

// Round 2
// 277.787 us; speedup vs baseline: 1.2534x; 1.1533x over previous
//
#include <hip/hip_runtime.h>
#include <hip/hip_fp16.h>
#include <math.h>

#define L_SIG 65537
#define NH    65536     // half-size complex FFT length (NFFT/2)
#define NSIG  256
#define PI_F  3.14159265358979323846f

struct alignas(8) c32 { float x, y; };   // 8B-aligned -> LDS ds_*_b64
typedef __half2 h2;
__device__ __forceinline__ c32 mkc(float a, float b){ c32 r; r.x=a; r.y=b; return r; }
__device__ __forceinline__ c32 cadd(c32 a, c32 b){ return mkc(a.x+b.x, a.y+b.y); }
__device__ __forceinline__ c32 csub(c32 a, c32 b){ return mkc(a.x-b.x, a.y-b.y); }
__device__ __forceinline__ c32 cmul(c32 a, c32 b){ return mkc(a.x*b.x - a.y*b.y, a.x*b.y + a.y*b.x); }
__device__ __forceinline__ h2  c2h(c32 a){ return __floats2half2_rn(a.x, a.y); }
__device__ __forceinline__ c32 h2c(h2 a){ float2 f = __half22float2(a); return mkc(f.x, f.y); }

// ---------------- 16-point FFT in registers (radix-4 x 2) ------------------
template<int S>
__device__ __forceinline__ void fft16(c32 v[16]) {
  constexpr float C16[16] = {
    1.0f, 0.9238795325112867f, 0.7071067811865476f, 0.3826834323650898f,
    0.0f,-0.3826834323650898f,-0.7071067811865476f,-0.9238795325112867f,
   -1.0f,-0.9238795325112867f,-0.7071067811865476f,-0.3826834323650898f,
    0.0f, 0.3826834323650898f, 0.7071067811865476f, 0.9238795325112867f };
  constexpr float S16[16] = {
    0.0f, 0.3826834323650898f, 0.7071067811865476f, 0.9238795325112867f,
    1.0f, 0.9238795325112867f, 0.7071067811865476f, 0.3826834323650898f,
    0.0f,-0.3826834323650898f,-0.7071067811865476f,-0.9238795325112867f,
   -1.0f,-0.9238795325112867f,-0.7071067811865476f,-0.3826834323650898f };
  c32 s[16];
  #pragma unroll
  for (int b0 = 0; b0 < 4; ++b0) {
    c32 x0=v[b0], x1=v[b0+4], x2=v[b0+8], x3=v[b0+12];
    c32 u0=cadd(x0,x2), u1=csub(x0,x2), u2=cadd(x1,x3), u3=csub(x1,x3);
    c32 iu3 = mkc(-u3.y, u3.x);
    c32 yy[4];
    yy[0]=cadd(u0,u2); yy[2]=csub(u0,u2);
    if (S < 0) { yy[1]=csub(u1,iu3); yy[3]=cadd(u1,iu3); }
    else       { yy[1]=cadd(u1,iu3); yy[3]=csub(u1,iu3); }
    #pragma unroll
    for (int c0 = 0; c0 < 4; ++c0) {
      const int p = (b0*c0) & 15;
      c32 w = mkc(C16[p], (S<0) ? -S16[p] : S16[p]);
      s[c0*4 + b0] = cmul(yy[c0], w);
    }
  }
  #pragma unroll
  for (int c0 = 0; c0 < 4; ++c0) {
    c32 x0=s[c0*4+0], x1=s[c0*4+1], x2=s[c0*4+2], x3=s[c0*4+3];
    c32 u0=cadd(x0,x2), u1=csub(x0,x2), u2=cadd(x1,x3), u3=csub(x1,x3);
    c32 iu3 = mkc(-u3.y, u3.x);
    c32 yy[4];
    yy[0]=cadd(u0,u2); yy[2]=csub(u0,u2);
    if (S < 0) { yy[1]=csub(u1,iu3); yy[3]=cadd(u1,iu3); }
    else       { yy[1]=cadd(u1,iu3); yy[3]=csub(u1,iu3); }
    v[c0+0]=yy[0]; v[c0+4]=yy[1]; v[c0+8]=yy[2]; v[c0+12]=yy[3];
  }
}

// ------------- 256-pt FFT, 16-thread team, c32(b64) XOR-swizzled LDS ------
// Banks (b64 view): write idx%16 = t ^ 8*(c&1); read idx%16 = t ^ 8*(r&1)
// -> 4 lanes per bank-pair = the 512B/wave-instr floor, no extra conflicts.
template<int S>
__device__ __forceinline__ void fft256_team(c32 v[16], int r, int t, c32* sc) {
  fft16<S>(v);
  float ang = (float)S * (2.0f*PI_F/256.0f) * (float)r;
  c32 st; __sincosf(ang, &st.y, &st.x);
  c32 w = st;
  #pragma unroll
  for (int c = 1; c < 16; ++c) { v[c] = cmul(v[c], w); w = cmul(w, st); }
  __syncthreads();
  #pragma unroll
  for (int c = 0; c < 16; ++c) {
    int idx = c*256 + ((r*16 + t) ^ ((c & 3) << 3));
    sc[idx] = v[c];
  }
  __syncthreads();
  #pragma unroll
  for (int a = 0; a < 16; ++a) {
    int idx = r*256 + ((a*16 + t) ^ ((r & 3) << 3));
    v[a] = sc[idx];
  }
  fft16<S>(v);
}

// ---------------- prep A: pm partial sums (md-separable) -------------------
// pm = (S0 + md*S1) / (65537*4),  S0 = sum cs(t),  S1 = sum cs(t)*sin(ang)
__global__ __launch_bounds__(256) void k_pm(const float* __restrict__ hp,
                                            float* __restrict__ pm_part) {
  __shared__ float r0[256], r1[256];
  int t = threadIdx.x, b = blockIdx.x;
  int gid = b*256 + t;
  float s0 = 0.f, s1 = 0.f;
  for (int tt = gid; tt < 65537; tt += 16384) {
    int ci = (tt * 8) / 65537;
    float cs = hp[ci*4+0] + hp[ci*4+1] + hp[ci*4+2] + hp[ci*4+3];
    float ang = (6.2831853071795864769f * (float)tt) / 65537.0f;
    s0 += cs;
    s1 += cs * sinf(ang);
  }
  r0[t] = s0; r1[t] = s1;
  __syncthreads();
  for (int s = 128; s > 0; s >>= 1) {
    if (t < s) { r0[t] += r0[t+s]; r1[t] += r1[t+s]; }
    __syncthreads();
  }
  if (t == 0) { pm_part[2*b] = r0[0]; pm_part[2*b+1] = r1[0]; }
}

// ---------------- prep B: MLP md, final pm, spectral line table ------------
__global__ __launch_bounds__(256) void k_prep2(const float* __restrict__ b1,
    const float* __restrict__ W2, const float* __restrict__ b2,
    const float* __restrict__ W3, const float* __restrict__ b3,
    const float* __restrict__ fw, const float* __restrict__ pm_part,
    float* __restrict__ pm_out, int* __restrict__ hidx, float* __restrict__ amp) {
  __shared__ float r0[64], r1[64];
  __shared__ float s_pm;
  int t = threadIdx.x;
  if (t < 64) { r0[t] = pm_part[2*t]; r1[t] = pm_part[2*t+1]; }
  __syncthreads();
  if (t == 0) {
    float h1[32], h2v[16];
    for (int i=0;i<32;i++){ float z = b1[i]; h1[i] = z > 0.f ? z : 0.f; }
    for (int o=0;o<16;o++){ float acc = b2[o];
      for (int i=0;i<32;i++) acc += h1[i]*W2[i*16+o];
      h2v[o] = acc > 0.f ? acc : 0.f; }
    float md = b3[1];
    for (int i=0;i<16;i++) md += h2v[i]*W3[i*8+1];
    float S0 = 0.f, S1 = 0.f;
    for (int i=0;i<64;i++){ S0 += r0[i]; S1 += r1[i]; }
    s_pm = (S0 + md*S1) / (65537.0f * 4.0f);
    pm_out[0] = s_pm;
  }
  __syncthreads();
  if (t < 40) {
    const double SPECF[8] = {7.83, 528.0, 396.0, 2.5, 14.1, 432.0, 6.0, 30.0};
    int j = t / 5, mi = t % 5;
    double mult = (double)(mi + 1);
    double hf = SPECF[j] * mult;
    double ratio = hf * (131072.0 / 22050.0);
    hidx[t] = (int)floor(ratio + 0.5);
    amp[t] = (float)((double)fw[j] * pow(mult, -1.2) * (1.0 + (double)s_pm));
  }
}

// ---------------- gain curve: bands + 40 spectral line windows ------------
__global__ __launch_bounds__(256) void k_gain(float* __restrict__ gain,
    const float* __restrict__ bw, const int* __restrict__ hidx,
    const float* __restrict__ amp) {
  int i = blockIdx.x*256 + threadIdx.x;
  if (i >= 65537) return;
  float f = (float)((double)i * (22050.0/131072.0));
  float g = 1.0f;
  constexpr double LO[6] = {1,4,8,13,30,100};
  constexpr double HI[6] = {4,8,13,30,100,200};
  #pragma unroll
  for (int k = 0; k < 6; ++k) {
    float center = (float)(0.5*(LO[k]+HI[k]));
    float sig    = (float)(0.25*(HI[k]-LO[k]));
    float dm = (f - center)/sig;
    float mask = expf(-0.5f*dm*dm);
    if (f < (float)LO[k] || f > (float)HI[k]) mask = 0.f;
    float ang = (float)(6.283185307179586*0.5*(LO[k]+HI[k])) * (float)i / 22050.0f;
    g *= 1.0f + mask * bw[k] * (1.0f + 0.2f*sinf(ang));
  }
  for (int l = 0; l < 40; ++l) {
    int d = i - hidx[l];
    if (d >= -15 && d <= 15) {
      float dd = (float)d * 0.2f;
      g *= 1.0f + amp[l] * expf(-0.5f*dd*dd);
    }
  }
  gain[i] = g;
}

// ---------------- forward pass 1: pack + column FFT + 4-step twiddle ------
__global__ __launch_bounds__(256) void k_fwd1(const float* __restrict__ x,
                                              h2* __restrict__ A, int s0) {
  __shared__ c32 sc[4096];           // 32 KB
  int b = blockIdx.x; int sl = b >> 4; int g = b & 15;
  int t = threadIdx.x & 15, r = threadIdx.x >> 4;
  int n1 = g*16 + t;
  const float* xb = x + (size_t)(s0 + sl) * L_SIG;
  c32 v[16];
  #pragma unroll
  for (int j = 0; j < 16; ++j) {
    int n = n1 + 256*r + 4096*j;
    c32 z = mkc(0.f, 0.f);
    if (n < 32768)       { z.x = xb[2*n]; z.y = xb[2*n+1]; }
    else if (n == 32768) { z.x = xb[65536]; }
    v[j] = z;
  }
  fft256_team<-1>(v, r, t, sc);
  float a0 = -(2.0f*PI_F/65536.0f) * (float)(n1 * r);
  float a1 = -(2.0f*PI_F/4096.0f)  * (float)n1;
  c32 wb, wst;
  __sincosf(a0, &wb.y, &wb.x);
  __sincosf(a1, &wst.y, &wst.x);
  #pragma unroll
  for (int j = 0; j < 16; ++j) { v[j] = cmul(v[j], wb); wb = cmul(wb, wst); }
  // stage + coalesced store: A[sl][k2*256 + n1]
  __syncthreads();
  #pragma unroll
  for (int j = 0; j < 16; ++j)
    sc[(r + 16*j)*16 + t] = v[j];     // bank-pair = t : floor
  __syncthreads();
  h2* Ab = A + (size_t)sl * NH;
  int u = threadIdx.x & 15, k2b = threadIdx.x >> 4;
  #pragma unroll
  for (int m = 0; m < 16; ++m) {
    int k2 = k2b + 16*m;
    Ab[(size_t)k2*256 + g*16 + u] = c2h(sc[k2*16 + u]);
  }
}

// ---------------- forward pass 2: row FFT -> Z natural order --------------
// stage-in: stg (h2, stride 260) aliases the team-FFT scratch (safe: fragments
// are in registers before fft256_team's first interior barrier).
__global__ __launch_bounds__(256) void k_fwd2(const h2* __restrict__ A,
                                              h2* __restrict__ B) {
  __shared__ c32 sc[4096];           // 32 KB; first 16.25 KB aliased as stg
  h2* stg = (h2*)sc;
  int b = blockIdx.x; int sl = b >> 4; int g = b & 15;
  int tid = threadIdx.x;
  int t = tid & 15, r = tid >> 4;
  const h2* Ab = A + (size_t)sl * NH;
  #pragma unroll
  for (int m = 0; m < 4; ++m) {
    int flat = tid + 256*m;
    int row = flat >> 6, i = flat & 63;
    float4 z = ((const float4*)(Ab + (size_t)(g*16 + row)*256))[i];
    *((float4*)&stg[row*260 + 4*i]) = z;   // 16B aligned, conflict-free
  }
  __syncthreads();
  c32 v[16];
  #pragma unroll
  for (int j = 0; j < 16; ++j)
    v[j] = h2c(stg[t*260 + r + 16*j]);     // banks (4t+r+16j)%32 : 2-way
  fft256_team<-1>(v, r, t, sc);
  h2* Bb = B + (size_t)sl * NH;
  int k2 = g*16 + t;
  #pragma unroll
  for (int j = 0; j < 16; ++j) Bb[(size_t)k2 + 256*(r + 16*j)] = c2h(v[j]);
}

// ---------------- mid: unpack + gain + mag smooth + repack + 1/N ----------
// Conjugate-pair sharing: with A=(zk+conj(zb))/2, B=(zk-conj(zb))/2 and
// w = -i e^{-i pi k/NH}:  X[k] = A + wB  and  X[NH-k] = conj(A - wB).
// One sincos + one cmul yields BOTH bins. Bins stored as unit-phase U and
// gained magnitude m (rsqrt, no sqrt/div); repack twiddle = stashed conj.
__global__ __launch_bounds__(256) void k_mid(const h2* __restrict__ Z,
    h2* __restrict__ Zc, const float* __restrict__ gain) {
  __shared__ c32 XL[258], XH[258];     // unit-phase vectors
  __shared__ float ML[258], MH[258];   // gained magnitudes
  __shared__ float TC[258], TS[258];   // cos/sin(pi*k/65536) at bin k=k0-1+e
  int b = blockIdx.x; int s = b >> 7; int blk = b & 127;
  int k0 = blk << 8;
  const h2* Zs = Z + (size_t)s * NH;
  h2* Os = Zc + (size_t)s * NH;
  int t = threadIdx.x;
  for (int e = t; e < 258; e += 256) {
    int k = k0 - 1 + e;                // bin for XL[e]; mirror NH-k -> XH[257-e]
    bool kv = (k >= 0);                // k==-1 only at blk==0,e==0 (mirror NH+1 also invalid)
    int kc = kv ? k : 0;
    c32 zk = h2c(Zs[k & (NH-1)]);
    c32 zb = h2c(Zs[(NH - k) & (NH-1)]);
    c32 Aa = mkc(0.5f*(zk.x + zb.x), 0.5f*(zk.y - zb.y));
    c32 Bm = mkc(0.5f*(zk.x - zb.x), 0.5f*(zk.y + zb.y));
    float sn, cn; __sincosf((PI_F/65536.0f)*(float)k, &sn, &cn);
    TC[e] = cn; TS[e] = sn;
    c32 wB = cmul(mkc(-sn, -cn), Bm);  // (-i e^{-i th}) * B
    float gk = gain[kc];
    float gK = gain[NH - kc];
    c32 Xk = mkc((Aa.x + wB.x)*gk,  (Aa.y + wB.y)*gk);    // X[k]*g[k]
    c32 XK = mkc((Aa.x - wB.x)*gK, -(Aa.y - wB.y)*gK);    // X[NH-k]*g[NH-k]
    float nk = Xk.x*Xk.x + Xk.y*Xk.y;
    float nK = XK.x*XK.x + XK.y*XK.y;
    float rk = rsqrtf(nk), rK = rsqrtf(nK);
    c32 Uk = (nk > 0.f) ? mkc(Xk.x*rk, Xk.y*rk) : mkc(1.f, 0.f);
    c32 UK = (nK > 0.f) ? mkc(XK.x*rK, XK.y*rK) : mkc(1.f, 0.f);
    float mk = (kv && nk > 0.f) ? nk*rk : 0.f;            // = |X|*g
    float mK = (kv && nK > 0.f) ? nK*rK : 0.f;
    XL[e] = Uk;  ML[e] = mk;
    XH[257-e] = UK; MH[257-e] = mK;
  }
  __syncthreads();
  {
    int q = t; int k = k0 + q;
    float m = ML[q+1];
    float msm = (k == 0) ? m : 0.7f*m + 0.15f*(ML[q] + ML[q+2]);
    c32 U = XL[q+1];
    c32 XcL = mkc(U.x*msm, U.y*msm);
    int K = NH - k;
    int eH = 256 - q;
    float mh = MH[eH];
    float msh = (K == 65536) ? mh : 0.7f*mh + 0.15f*(MH[eH-1] + MH[eH+1]);
    c32 Uh = XH[eH];
    c32 XcH = mkc(Uh.x*msh, Uh.y*msh);
    // E' = 0.5(XcL + conj(XcH)); O' = 0.5 W^{-k} (XcL - conj(XcH))
    c32 E = mkc(0.5f*(XcL.x + XcH.x), 0.5f*(XcL.y - XcH.y));
    c32 D = mkc(0.5f*(XcL.x - XcH.x), 0.5f*(XcL.y + XcH.y));
    c32 O = cmul(mkc(TC[q+1], TS[q+1]), D);   // e^{+i pi k/NH} = conj(unpack tw)
    const float invN = 1.0f/65536.0f;
    Os[k] = c2h(mkc((E.x - O.y)*invN, (E.y + O.x)*invN));              // E' + iO'
    if (k != 0) Os[K] = c2h(mkc((E.x + O.y)*invN, (O.x - E.y)*invN));  // conj pack
  }
  if (blk == 127 && t == 0) {   // self-paired bin k = 32768
    float m = ML[257];
    float msm = 0.7f*m + 0.15f*(ML[256] + MH[1]);
    c32 U = XL[257];
    const float invN = 1.0f/65536.0f;
    Os[32768] = c2h(mkc(U.x*msm*invN, -U.y*msm*invN));
  }
}

// ---------------- inverse pass 1: column FFT (+) + twiddle ----------------
__global__ __launch_bounds__(256) void k_inv1(const h2* __restrict__ Zc,
                                              h2* __restrict__ B) {
  __shared__ c32 sc[4096];
  int b = blockIdx.x; int sl = b >> 4; int g = b & 15;
  int t = threadIdx.x & 15, r = threadIdx.x >> 4;
  int a = g*16 + t;
  const h2* Zs = Zc + (size_t)sl * NH;
  c32 v[16];
  #pragma unroll
  for (int j = 0; j < 16; ++j) v[j] = h2c(Zs[(size_t)a + 256*(r + 16*j)]);
  fft256_team<1>(v, r, t, sc);
  float a0 = (2.0f*PI_F/65536.0f) * (float)(a * r);
  float a1 = (2.0f*PI_F/4096.0f)  * (float)a;
  c32 wb, wst;
  __sincosf(a0, &wb.y, &wb.x);
  __sincosf(a1, &wst.y, &wst.x);
  #pragma unroll
  for (int j = 0; j < 16; ++j) { v[j] = cmul(v[j], wb); wb = cmul(wb, wst); }
  __syncthreads();
  #pragma unroll
  for (int j = 0; j < 16; ++j)
    sc[(r + 16*j)*16 + t] = v[j];
  __syncthreads();
  h2* Bb = B + (size_t)sl * NH;
  int u = threadIdx.x & 15, m2b = threadIdx.x >> 4;
  #pragma unroll
  for (int m = 0; m < 16; ++m) {
    int m2 = m2b + 16*m;
    Bb[(size_t)m2*256 + g*16 + u] = c2h(sc[m2*16 + u]);
  }
}

// ---------------- inverse pass 2: row FFT (+) -> real output --------------
__global__ __launch_bounds__(256) void k_inv2(const h2* __restrict__ B,
                                              float* __restrict__ out, int s0) {
  __shared__ c32 sc[4096];
  h2* stg = (h2*)sc;
  int b = blockIdx.x; int sl = b >> 4; int g = b & 15;
  int tid = threadIdx.x;
  int t = tid & 15, r = tid >> 4;
  const h2* Bb = B + (size_t)sl * NH;
  #pragma unroll
  for (int m = 0; m < 4; ++m) {
    int flat = tid + 256*m;
    int row = flat >> 6, i = flat & 63;
    float4 z = ((const float4*)(Bb + (size_t)(g*16 + row)*256))[i];
    *((float4*)&stg[row*260 + 4*i]) = z;
  }
  __syncthreads();
  c32 v[16];
  #pragma unroll
  for (int j = 0; j < 16; ++j)
    v[j] = h2c(stg[t*260 + r + 16*j]);
  fft256_team<1>(v, r, t, sc);
  float* yb = out + (size_t)(s0 + sl) * L_SIG;
  int m2 = g*16 + t;
  #pragma unroll
  for (int j = 0; j < 16; ++j) {
    int m1 = r + 16*j;
    if (m1 <= 127) {
      int m = m2 + 256*m1;
      yb[2*m]   = v[j].x;
      yb[2*m+1] = v[j].y;
    } else if (m1 == 128 && m2 == 0) {
      yb[65536] = v[j].x;
    }
  }
}

// --------------------------------------------------------------------------
extern "C" void kernel_launch(void* const* d_in, const int* in_sizes, int n_in,
                              void* d_out, int out_size, void* d_ws, size_t ws_size,
                              hipStream_t stream) {
  const float* x  = (const float*)d_in[0];
  const float* bw = (const float*)d_in[1];
  const float* fw = (const float*)d_in[2];
  const float* hp = (const float*)d_in[3];
  // d_in[4] = W1: mathematically unused (tn==0 at the only sampled row)
  const float* b1 = (const float*)d_in[5];
  const float* W2 = (const float*)d_in[6];
  const float* b2 = (const float*)d_in[7];
  const float* W3 = (const float*)d_in[8];
  const float* b3 = (const float*)d_in[9];
  float* out = (float*)d_out;
  char* ws = (char*)d_ws;

  const size_t perSig = (size_t)NH * sizeof(h2);              // 256 KiB / signal / buffer
  const size_t tail   = (size_t)L_SIG * sizeof(float) + 2048; // gain + scalars + pm_part
  size_t cap = (ws_size > tail) ? (ws_size - tail) / (2*perSig) : 1;
  int chunk = (cap >= (size_t)NSIG) ? NSIG : (cap < 1 ? 1 : (int)cap);

  h2*    A    = (h2*)ws;
  h2*    Bb   = (h2*)(ws + (size_t)chunk*perSig);
  float* gain = (float*)(ws + 2*(size_t)chunk*perSig);
  float* pm   = gain + L_SIG;
  int*   hidx = (int*)(pm + 1);
  float* amp  = (float*)(hidx + 40);
  float* pm_part = amp + 40;          // 128 floats

  k_pm   <<<64, 256, 0, stream>>>(hp, pm_part);
  k_prep2<<<1,  256, 0, stream>>>(b1, W2, b2, W3, b3, fw, pm_part, pm, hidx, amp);
  k_gain <<<257,256, 0, stream>>>(gain, bw, hidx, amp);

  for (int s0 = 0; s0 < NSIG; s0 += chunk) {
    int S = (NSIG - s0 < chunk) ? (NSIG - s0) : chunk;
    k_fwd1<<<S*16, 256, 0, stream>>>(x, A, s0);
    k_fwd2<<<S*16, 256, 0, stream>>>(A, Bb);
    k_mid <<<S*128,256, 0, stream>>>(Bb, A, gain);
    k_inv1<<<S*16, 256, 0, stream>>>(A, Bb);
    k_inv2<<<S*16, 256, 0, stream>>>(Bb, out, s0);
  }
}